// Round 8
// baseline (57.908 us; speedup 1.0000x reference)
//
#include <hip/hip_runtime.h>

#define Q 8                // index-stripes per person (also sample partition)

// workspace layout
//   part  @ 1024     (n*Q floats)
//   c4g   @ 8192     (n*4 floats: cx,cy,cz,s per person)
//   ggrid @ 65536    (n * 32768 ints: full 32^3 d^2 grid per person)

// ---------------------------------------------------------------------------
// R20: index-balanced 4-kernel pipeline. Spatial x-slab partitioning (R13)
// is ~all-on-2-of-8-slabs imbalanced for Gaussian clouds; here every block
// owns an equal V/8 stripe of vertices for both raster and sample, and the
// 32^3 grid lives in global memory (device-scope atomicMin, no return).
// c4 and grid contents are bit-identical to R13; only part[] regrouping
// changes (R16 precedent: absmax stayed 0.0 under regrouping).
// ---------------------------------------------------------------------------

// --- k_pre: init grid + bounds/c4 (q==0 blocks) ----------------------------
__global__ __launch_bounds__(1024) void k_pre(const float* __restrict__ verts,
                                              const float* __restrict__ trans,
                                              float* __restrict__ c4g,
                                              int* __restrict__ ggrid,
                                              int V, int n) {
    __shared__ float red[16][6];
    int bq  = blockIdx.x;
    int p   = bq / Q;
    int q   = bq - p * Q;
    int tid = threadIdx.x, lane = tid & 63, wave = tid >> 6;

    // fill this block's grid slice: 4096 ints = 1024 threads x int4
    int4* slice = (int4*)(ggrid + (size_t)p * 32768 + q * 4096);
    slice[tid] = make_int4(0x7F7F7F7F, 0x7F7F7F7F, 0x7F7F7F7F, 0x7F7F7F7F);

    if (q != 0) return;

    // bounds scan (identical code/order to R13 -> bit-identical c4)
    const float* vp = verts + (size_t)p * V * 3;
    float mnx = 3.4e38f, mny = 3.4e38f, mnz = 3.4e38f;
    float mxx = -3.4e38f, mxy = -3.4e38f, mxz = -3.4e38f;
    for (int j = tid; j < V; j += 1024) {
        float x = vp[3 * j + 0], y = vp[3 * j + 1], z = vp[3 * j + 2];
        mnx = fminf(mnx, x); mxx = fmaxf(mxx, x);
        mny = fminf(mny, y); mxy = fmaxf(mxy, y);
        mnz = fminf(mnz, z); mxz = fmaxf(mxz, z);
    }
    for (int m = 32; m > 0; m >>= 1) {
        mnx = fminf(mnx, __shfl_xor(mnx, m)); mxx = fmaxf(mxx, __shfl_xor(mxx, m));
        mny = fminf(mny, __shfl_xor(mny, m)); mxy = fmaxf(mxy, __shfl_xor(mxy, m));
        mnz = fminf(mnz, __shfl_xor(mnz, m)); mxz = fmaxf(mxz, __shfl_xor(mxz, m));
    }
    if (lane == 0) {
        red[wave][0] = mnx; red[wave][1] = mny; red[wave][2] = mnz;
        red[wave][3] = mxx; red[wave][4] = mxy; red[wave][5] = mxz;
    }
    __syncthreads();
    if (tid == 0) {
        float a0 = red[0][0], a1 = red[0][1], a2 = red[0][2];
        float b0 = red[0][3], b1 = red[0][4], b2 = red[0][5];
        for (int w = 1; w < 16; ++w) {
            a0 = fminf(a0, red[w][0]); a1 = fminf(a1, red[w][1]); a2 = fminf(a2, red[w][2]);
            b0 = fmaxf(b0, red[w][3]); b1 = fmaxf(b1, red[w][4]); b2 = fmaxf(b2, red[w][5]);
        }
        float tx = trans[p * 3 + 0], ty = trans[p * 3 + 1], tz = trans[p * 3 + 2];
        float scale = 0.6f * fmaxf(b0 - a0, fmaxf(b1 - a1, b2 - a2));  // (1+0.2)*0.5
        c4g[4 * p + 0] = 0.5f * (a0 + b0) + tx;
        c4g[4 * p + 1] = 0.5f * (a1 + b1) + ty;
        c4g[4 * p + 2] = 0.5f * (a2 + b2) + tz;
        c4g[4 * p + 3] = scale;
    }
}

// --- k_raster: balanced vertex-stripe scatter to global grid ---------------
__global__ __launch_bounds__(1024) void k_raster(const float* __restrict__ verts,
                                                 const float* __restrict__ trans,
                                                 const float* __restrict__ c4g,
                                                 int* __restrict__ ggrid,
                                                 int V, int n) {
    int bq  = blockIdx.x;
    int p   = bq / Q;
    int q   = bq - p * Q;
    int tid = threadIdx.x;

    float cx = c4g[4 * p + 0], cy = c4g[4 * p + 1];
    float cz = c4g[4 * p + 2], s  = c4g[4 * p + 3];
    float inv = 1.0f / s;
    float tx = trans[p * 3 + 0], ty = trans[p * 3 + 1], tz = trans[p * 3 + 2];
    float rg = (4.65f * inv) * 1.0005f + 0.005f;
    const float step = 2.0f / 31.0f;

    const float* vp = verts + (size_t)p * V * 3;
    int* gg = ggrid + (size_t)p * 32768;

    int jlo = (q * V) / Q, jhi = ((q + 1) * V) / Q;
    for (int j = jlo + tid; j < jhi; j += 1024) {
        float wx = vp[3 * j + 0] + tx;
        float wy = vp[3 * j + 1] + ty;
        float wz = vp[3 * j + 2] + tz;
        float gvx = ((wx - cx) * inv + 1.0f) * 15.5f;
        float gvy = ((wy - cy) * inv + 1.0f) * 15.5f;
        float gvz = ((wz - cz) * inv + 1.0f) * 15.5f;
        int x0 = max(0, (int)ceilf(gvx - rg)), x1 = min(31, (int)floorf(gvx + rg));
        int y0 = max(0, (int)ceilf(gvy - rg)), y1 = min(31, (int)floorf(gvy + rg));
        int z0 = max(0, (int)ceilf(gvz - rg)), z1 = min(31, (int)floorf(gvz + rg));
        for (int xi = x0; xi <= x1; ++xi) {
            float qx = fmaf((float)xi, step, -1.0f) * s + cx;
            float dx = qx - wx;
            float dx2 = dx * dx;
            if (dx2 >= 0.09f) continue;
            for (int yi = y0; yi <= y1; ++yi) {
                float qy = fmaf((float)yi, step, -1.0f) * s + cy;
                float dy = qy - wy;
                float dxy = fmaf(dy, dy, dx2);
                if (dxy >= 0.09f) continue;
                for (int zi = z0; zi <= z1; ++zi) {
                    float qz = fmaf((float)zi, step, -1.0f) * s + cz;
                    float dz = qz - wz;
                    float d2 = fmaf(dz, dz, dxy);
                    if (d2 < 0.09f)
                        atomicMin(&gg[(xi << 10) | (yi << 5) | zi],
                                  __float_as_int(d2));   // no return use -> no wait
                }
            }
        }
    }
}

// --- k_sample: balanced vertex-stripe trilinear sampling -------------------
__global__ __launch_bounds__(1024) void k_sample(const float* __restrict__ verts,
                                                 const float* __restrict__ trans,
                                                 const float* __restrict__ c4g,
                                                 const int* __restrict__ ggrid,
                                                 float* __restrict__ part,
                                                 int V, int n,
                                                 const int* __restrict__ pP) {
    __shared__ float racc[16];
    int bq  = blockIdx.x;
    int p   = bq / Q;
    int q   = bq - p * Q;
    int tid = threadIdx.x, lane = tid & 63, wave = tid >> 6;

    float cx = c4g[4 * p + 0], cy = c4g[4 * p + 1];
    float cz = c4g[4 * p + 2], s  = c4g[4 * p + 3];
    const int* gg = ggrid + (size_t)p * 32768;

    int P = *pP;
    int f = p / P, iloc = p - f * P;
    int jlo = (q * V) / Q, jhi = ((q + 1) * V) / Q;

    float acc = 0.0f;
    for (int jp = 0; jp < P; ++jp) {
        if (jp == iloc) continue;
        int pj = f * P + jp;
        const float* vj = verts + (size_t)pj * V * 3;
        float tjx = trans[pj * 3 + 0], tjy = trans[pj * 3 + 1], tjz = trans[pj * 3 + 2];
        for (int v = jlo + tid; v < jhi; v += 1024) {
            float wx = vj[3 * v + 0] + tjx;
            float wy = vj[3 * v + 1] + tjy;
            float wz = vj[3 * v + 2] + tjz;
            float gx = fminf(fmaxf(((wx - cx) / s + 1.0f) * 15.5f, 0.0f), 31.0f);
            float gy = fminf(fmaxf(((wy - cy) / s + 1.0f) * 15.5f, 0.0f), 31.0f);
            float gz = fminf(fmaxf(((wz - cz) / s + 1.0f) * 15.5f, 0.0f), 31.0f);
            int x0 = min((int)gx, 30);
            int y0 = min((int)gy, 30);
            int z0 = min((int)gz, 30);
            float fx = gx - (float)x0;
            float fy = gy - (float)y0;
            float fz = gz - (float)z0;
            int b = (x0 << 10) | (y0 << 5) | z0;
            float c000 = fmaxf(0.3f - sqrtf(__int_as_float(gg[b])), 0.0f);
            float c100 = fmaxf(0.3f - sqrtf(__int_as_float(gg[b + 1024])), 0.0f);
            float c010 = fmaxf(0.3f - sqrtf(__int_as_float(gg[b + 32])), 0.0f);
            float c110 = fmaxf(0.3f - sqrtf(__int_as_float(gg[b + 1056])), 0.0f);
            float c001 = fmaxf(0.3f - sqrtf(__int_as_float(gg[b + 1])), 0.0f);
            float c101 = fmaxf(0.3f - sqrtf(__int_as_float(gg[b + 1025])), 0.0f);
            float c011 = fmaxf(0.3f - sqrtf(__int_as_float(gg[b + 33])), 0.0f);
            float c111 = fmaxf(0.3f - sqrtf(__int_as_float(gg[b + 1057])), 0.0f);
            float c00 = c000 * (1.0f - fx) + c100 * fx;
            float c10 = c010 * (1.0f - fx) + c110 * fx;
            float c01 = c001 * (1.0f - fx) + c101 * fx;
            float c11 = c011 * (1.0f - fx) + c111 * fx;
            float c0 = c00 * (1.0f - fy) + c10 * fy;
            float c1 = c01 * (1.0f - fy) + c11 * fy;
            float sv = c0 * (1.0f - fz) + c1 * fz;
            acc += fmaxf(sv, 0.0f);
        }
    }
    for (int m = 32; m > 0; m >>= 1) acc += __shfl_xor(acc, m);
    if (lane == 0) racc[wave] = acc;
    __syncthreads();
    if (tid == 0) {
        float t = 0.0f;
        for (int w = 0; w < 16; ++w) t += racc[w];
        part[bq] = t;                       // unconditional -> no zero-init
    }
}

// --- k_final: parallel weighted reduction (R12-proven, unchanged) ----------
__global__ __launch_bounds__(256) void k_final(const float* __restrict__ part,
                                               const int* __restrict__ valid,
                                               const int* __restrict__ pP,
                                               float* __restrict__ out, int n) {
    __shared__ float snum[4], sden[4];
    int P = *pP;
    int F = n / P;
    int tot = n * Q;
    int tid = threadIdx.x, lane = tid & 63, wave = tid >> 6;
    float num = 0.0f;
    for (int i = tid; i < tot; i += 256) {
        int f = i / (P * Q);
        num += part[i] * (float)valid[f * P];
    }
    float den = 0.0f;
    for (int f = tid; f < F; f += 256) den += (float)valid[f * P];
    for (int m = 32; m > 0; m >>= 1) {
        num += __shfl_xor(num, m);
        den += __shfl_xor(den, m);
    }
    if (lane == 0) { snum[wave] = num; sden[wave] = den; }
    __syncthreads();
    if (tid == 0) {
        float tn = snum[0] + snum[1] + snum[2] + snum[3];
        float td = sden[0] + sden[1] + sden[2] + sden[3];
        out[0] = tn / td * (1000.0f / (float)(P * P));
    }
}

// ---------------------------------------------------------------------------
extern "C" void kernel_launch(void* const* d_in, const int* in_sizes, int n_in,
                              void* d_out, int out_size, void* d_ws, size_t ws_size,
                              hipStream_t stream) {
    const float* verts = (const float*)d_in[0];
    const float* trans = (const float*)d_in[1];
    const int*   valid = (const int*)d_in[2];       // int32 on device (harness)
    const int*   pP    = (const int*)d_in[5];       // num_people (device scalar)

    int n = in_sizes[1] / 3;                        // total persons
    int V = in_sizes[0] / in_sizes[1];              // vertices per person

    float* part  = (float*)((char*)d_ws + 1024);    // n*Q floats
    float* c4g   = (float*)((char*)d_ws + 8192);    // n*4 floats
    int*   ggrid = (int*)((char*)d_ws + 65536);     // n*32768 ints

    k_pre   <<<n * Q, 1024, 0, stream>>>(verts, trans, c4g, ggrid, V, n);
    k_raster<<<n * Q, 1024, 0, stream>>>(verts, trans, c4g, ggrid, V, n);
    k_sample<<<n * Q, 1024, 0, stream>>>(verts, trans, c4g, ggrid, part, V, n, pP);
    k_final <<<1, 256, 0, stream>>>(part, valid, pP, (float*)d_out, n);
}

// Round 9
// 32.234 us; speedup vs baseline: 1.7965x; 1.7965x over previous
//
#include <hip/hip_runtime.h>

#define Q 8                // index-stripes per person (sample partition; grid = n*Q blocks)
#define NR 8               // register-held verts per thread (covers V <= 8192)

// ---------------------------------------------------------------------------
// R21: redundant-full-raster. One block per (person, stripe). Every block
// builds its person's FULL 32^3 grid in 128 KB LDS straight from registers
// (no filter scan, no ballot queue, no drain, no slab imbalance -- all 256
// blocks do identical work), then samples its V/8 index-stripe of the other
// person(s) gate-free. Grid is an exact atomicMin over the identical
// candidate set as R13 (slab-union = full grid) with bit-identical c4;
// sample arithmetic is R20's gate-free form (absmax 0.0 precedent).
// LDS atomics only (R8 lesson: global atomics write through to HBM).
// ---------------------------------------------------------------------------
__global__ __launch_bounds__(1024) void k_fused(const float* __restrict__ verts,
                                                const float* __restrict__ trans,
                                                float* __restrict__ part,
                                                int V, int n,
                                                const int* __restrict__ pP) {
    __shared__ int   grid[32 * 1024];      // full 32^3 d^2 bits, 128 KB
    __shared__ float red[16][6];
    __shared__ float c4s[4];
    __shared__ float racc[16];

    int bq  = blockIdx.x;
    int p   = bq / Q;
    int q   = bq - p * Q;
    int tid = threadIdx.x, lane = tid & 63, wave = tid >> 6;

    // init full grid: 8192 int4 stores, 8 per thread, conflict-free
    {
        int4* g4 = (int4*)grid;
        int4  fill = make_int4(0x7F7F7F7F, 0x7F7F7F7F, 0x7F7F7F7F, 0x7F7F7F7F);
        #pragma unroll
        for (int k = 0; k < 8; ++k) g4[tid + (k << 10)] = fill;
    }

    const float* vp = verts + (size_t)p * V * 3;

    // --- 1. load own verts into registers + bounds (identical to R13) -----
    float rx[NR], ry[NR], rz[NR];
    {
        float mnx = 3.4e38f, mny = 3.4e38f, mnz = 3.4e38f;
        float mxx = -3.4e38f, mxy = -3.4e38f, mxz = -3.4e38f;
        #pragma unroll
        for (int r = 0; r < NR; ++r) {
            int j = tid + (r << 10);
            if (j < V) {
                float x = vp[3 * j + 0], y = vp[3 * j + 1], z = vp[3 * j + 2];
                rx[r] = x; ry[r] = y; rz[r] = z;
                mnx = fminf(mnx, x); mxx = fmaxf(mxx, x);
                mny = fminf(mny, y); mxy = fmaxf(mxy, y);
                mnz = fminf(mnz, z); mxz = fmaxf(mxz, z);
            } else {
                rx[r] = 0.0f; ry[r] = 0.0f; rz[r] = 0.0f;
            }
        }
        // streamed tail (only if V > NR*1024; never taken for V=6890)
        for (int j = tid + (NR << 10); j < V; j += 1024) {
            float x = vp[3 * j + 0], y = vp[3 * j + 1], z = vp[3 * j + 2];
            mnx = fminf(mnx, x); mxx = fmaxf(mxx, x);
            mny = fminf(mny, y); mxy = fmaxf(mxy, y);
            mnz = fminf(mnz, z); mxz = fmaxf(mxz, z);
        }
        for (int m = 32; m > 0; m >>= 1) {
            mnx = fminf(mnx, __shfl_xor(mnx, m)); mxx = fmaxf(mxx, __shfl_xor(mxx, m));
            mny = fminf(mny, __shfl_xor(mny, m)); mxy = fmaxf(mxy, __shfl_xor(mxy, m));
            mnz = fminf(mnz, __shfl_xor(mnz, m)); mxz = fmaxf(mxz, __shfl_xor(mxz, m));
        }
        if (lane == 0) {
            red[wave][0] = mnx; red[wave][1] = mny; red[wave][2] = mnz;
            red[wave][3] = mxx; red[wave][4] = mxy; red[wave][5] = mxz;
        }
        __syncthreads();
        if (tid == 0) {
            float a0 = red[0][0], a1 = red[0][1], a2 = red[0][2];
            float b0 = red[0][3], b1 = red[0][4], b2 = red[0][5];
            for (int w = 1; w < 16; ++w) {
                a0 = fminf(a0, red[w][0]); a1 = fminf(a1, red[w][1]); a2 = fminf(a2, red[w][2]);
                b0 = fmaxf(b0, red[w][3]); b1 = fmaxf(b1, red[w][4]); b2 = fmaxf(b2, red[w][5]);
            }
            float tx = trans[p * 3 + 0], ty = trans[p * 3 + 1], tz = trans[p * 3 + 2];
            float scale = 0.6f * fmaxf(b0 - a0, fmaxf(b1 - a1, b2 - a2));  // (1+0.2)*0.5
            c4s[0] = 0.5f * (a0 + b0) + tx;
            c4s[1] = 0.5f * (a1 + b1) + ty;
            c4s[2] = 0.5f * (a2 + b2) + tz;
            c4s[3] = scale;
        }
        __syncthreads();
    }
    float cx = c4s[0], cy = c4s[1], cz = c4s[2], s = c4s[3];
    float inv = 1.0f / s;
    float tx = trans[p * 3 + 0], ty = trans[p * 3 + 1], tz = trans[p * 3 + 2];
    float rg = (4.65f * inv) * 1.0005f + 0.005f;
    const float step = 2.0f / 31.0f;

    // --- 2. raster ALL verts from registers into the full LDS grid --------
    // (same per-vert arithmetic chain as R13's drain; full [0,31] clamps)
    #pragma unroll
    for (int r = 0; r < NR; ++r) {
        int j = tid + (r << 10);
        if (j < V) {
            float wx = rx[r] + tx;
            float wy = ry[r] + ty;
            float wz = rz[r] + tz;
            float gvx = ((wx - cx) * inv + 1.0f) * 15.5f;
            float gvy = ((wy - cy) * inv + 1.0f) * 15.5f;
            float gvz = ((wz - cz) * inv + 1.0f) * 15.5f;
            int x0 = max(0, (int)ceilf(gvx - rg)), x1 = min(31, (int)floorf(gvx + rg));
            int y0 = max(0, (int)ceilf(gvy - rg)), y1 = min(31, (int)floorf(gvy + rg));
            int z0 = max(0, (int)ceilf(gvz - rg)), z1 = min(31, (int)floorf(gvz + rg));
            for (int xi = x0; xi <= x1; ++xi) {
                float qx = fmaf((float)xi, step, -1.0f) * s + cx;
                float dx = qx - wx;
                float dx2 = dx * dx;
                if (dx2 >= 0.09f) continue;
                for (int yi = y0; yi <= y1; ++yi) {
                    float qy = fmaf((float)yi, step, -1.0f) * s + cy;
                    float dy = qy - wy;
                    float dxy = fmaf(dy, dy, dx2);
                    if (dxy >= 0.09f) continue;
                    for (int zi = z0; zi <= z1; ++zi) {
                        float qz = fmaf((float)zi, step, -1.0f) * s + cz;
                        float dz = qz - wz;
                        float d2 = fmaf(dz, dz, dxy);
                        if (d2 < 0.09f)
                            atomicMin(&grid[(xi << 10) | (yi << 5) | zi],
                                      __float_as_int(d2));
                    }
                }
            }
        }
    }
    // streamed tail (V > NR*1024 only): raster directly from global
    for (int j = tid + (NR << 10); j < V; j += 1024) {
        float wx = vp[3 * j + 0] + tx;
        float wy = vp[3 * j + 1] + ty;
        float wz = vp[3 * j + 2] + tz;
        float gvx = ((wx - cx) * inv + 1.0f) * 15.5f;
        float gvy = ((wy - cy) * inv + 1.0f) * 15.5f;
        float gvz = ((wz - cz) * inv + 1.0f) * 15.5f;
        int x0 = max(0, (int)ceilf(gvx - rg)), x1 = min(31, (int)floorf(gvx + rg));
        int y0 = max(0, (int)ceilf(gvy - rg)), y1 = min(31, (int)floorf(gvy + rg));
        int z0 = max(0, (int)ceilf(gvz - rg)), z1 = min(31, (int)floorf(gvz + rg));
        for (int xi = x0; xi <= x1; ++xi) {
            float qx = fmaf((float)xi, step, -1.0f) * s + cx;
            float dx = qx - wx;
            float dx2 = dx * dx;
            if (dx2 >= 0.09f) continue;
            for (int yi = y0; yi <= y1; ++yi) {
                float qy = fmaf((float)yi, step, -1.0f) * s + cy;
                float dy = qy - wy;
                float dxy = fmaf(dy, dy, dx2);
                if (dxy >= 0.09f) continue;
                for (int zi = z0; zi <= z1; ++zi) {
                    float qz = fmaf((float)zi, step, -1.0f) * s + cz;
                    float dz = qz - wz;
                    float d2 = fmaf(dz, dz, dxy);
                    if (d2 < 0.09f)
                        atomicMin(&grid[(xi << 10) | (yi << 5) | zi],
                                  __float_as_int(d2));
                }
            }
        }
    }
    __syncthreads();

    // --- 3. sample: index-stripe of each other person, gate-free ----------
    int P = *pP;
    int f = p / P, iloc = p - f * P;
    int jlo = (q * V) / Q, jhi = ((q + 1) * V) / Q;
    float acc = 0.0f;
    for (int jp = 0; jp < P; ++jp) {
        if (jp == iloc) continue;
        int pj = f * P + jp;
        const float* vj = verts + (size_t)pj * V * 3;
        float tjx = trans[pj * 3 + 0], tjy = trans[pj * 3 + 1], tjz = trans[pj * 3 + 2];
        for (int v = jlo + tid; v < jhi; v += 1024) {
            float wx = vj[3 * v + 0] + tjx;
            float wy = vj[3 * v + 1] + tjy;
            float wz = vj[3 * v + 2] + tjz;
            float gx = fminf(fmaxf(((wx - cx) / s + 1.0f) * 15.5f, 0.0f), 31.0f);
            float gy = fminf(fmaxf(((wy - cy) / s + 1.0f) * 15.5f, 0.0f), 31.0f);
            float gz = fminf(fmaxf(((wz - cz) / s + 1.0f) * 15.5f, 0.0f), 31.0f);
            int x0 = min((int)gx, 30);
            int y0 = min((int)gy, 30);
            int z0 = min((int)gz, 30);
            float fx = gx - (float)x0;
            float fy = gy - (float)y0;
            float fz = gz - (float)z0;
            int b = (x0 << 10) | (y0 << 5) | z0;
            float c000 = fmaxf(0.3f - sqrtf(__int_as_float(grid[b])), 0.0f);
            float c100 = fmaxf(0.3f - sqrtf(__int_as_float(grid[b + 1024])), 0.0f);
            float c010 = fmaxf(0.3f - sqrtf(__int_as_float(grid[b + 32])), 0.0f);
            float c110 = fmaxf(0.3f - sqrtf(__int_as_float(grid[b + 1056])), 0.0f);
            float c001 = fmaxf(0.3f - sqrtf(__int_as_float(grid[b + 1])), 0.0f);
            float c101 = fmaxf(0.3f - sqrtf(__int_as_float(grid[b + 1025])), 0.0f);
            float c011 = fmaxf(0.3f - sqrtf(__int_as_float(grid[b + 33])), 0.0f);
            float c111 = fmaxf(0.3f - sqrtf(__int_as_float(grid[b + 1057])), 0.0f);
            float c00 = c000 * (1.0f - fx) + c100 * fx;
            float c10 = c010 * (1.0f - fx) + c110 * fx;
            float c01 = c001 * (1.0f - fx) + c101 * fx;
            float c11 = c011 * (1.0f - fx) + c111 * fx;
            float c0 = c00 * (1.0f - fy) + c10 * fy;
            float c1 = c01 * (1.0f - fy) + c11 * fy;
            float sv = c0 * (1.0f - fz) + c1 * fz;
            acc += fmaxf(sv, 0.0f);
        }
    }
    for (int m = 32; m > 0; m >>= 1) acc += __shfl_xor(acc, m);
    if (lane == 0) racc[wave] = acc;
    __syncthreads();
    if (tid == 0) {
        float t = 0.0f;
        for (int w = 0; w < 16; ++w) t += racc[w];
        part[bq] = t;                       // unconditional -> no zero-init
    }
}

// ---------------------------------------------------------------------------
// Final: parallel weighted reduction (R12-proven, unchanged).
// ---------------------------------------------------------------------------
__global__ __launch_bounds__(256) void k_final(const float* __restrict__ part,
                                               const int* __restrict__ valid,
                                               const int* __restrict__ pP,
                                               float* __restrict__ out, int n) {
    __shared__ float snum[4], sden[4];
    int P = *pP;
    int F = n / P;
    int tot = n * Q;
    int tid = threadIdx.x, lane = tid & 63, wave = tid >> 6;
    float num = 0.0f;
    for (int i = tid; i < tot; i += 256) {
        int f = i / (P * Q);
        num += part[i] * (float)valid[f * P];
    }
    float den = 0.0f;
    for (int f = tid; f < F; f += 256) den += (float)valid[f * P];
    for (int m = 32; m > 0; m >>= 1) {
        num += __shfl_xor(num, m);
        den += __shfl_xor(den, m);
    }
    if (lane == 0) { snum[wave] = num; sden[wave] = den; }
    __syncthreads();
    if (tid == 0) {
        float tn = snum[0] + snum[1] + snum[2] + snum[3];
        float td = sden[0] + sden[1] + sden[2] + sden[3];
        out[0] = tn / td * (1000.0f / (float)(P * P));
    }
}

// ---------------------------------------------------------------------------
extern "C" void kernel_launch(void* const* d_in, const int* in_sizes, int n_in,
                              void* d_out, int out_size, void* d_ws, size_t ws_size,
                              hipStream_t stream) {
    const float* verts = (const float*)d_in[0];
    const float* trans = (const float*)d_in[1];
    const int*   valid = (const int*)d_in[2];       // int32 on device (harness)
    const int*   pP    = (const int*)d_in[5];       // num_people (device scalar)

    int n = in_sizes[1] / 3;                        // total persons
    int V = in_sizes[0] / in_sizes[1];              // vertices per person

    float* part = (float*)d_ws;                     // n*Q floats

    k_fused<<<n * Q, 1024, 0, stream>>>(verts, trans, part, V, n, pP);
    k_final<<<1, 256, 0, stream>>>(part, valid, pP, (float*)d_out, n);
}